// Round 7
// baseline (368.716 us; speedup 1.0000x reference)
//
#include <hip/hip_runtime.h>
#include <math.h>

// SchNet interaction, MFMA bf16-split. Nb=8, Na=1024, Nnbh=64, A=F=128, S=50.

#define RCUT  5.0f
#define LOG2F_ 0.69314718055994530942f

typedef __bf16 bf16x8_t __attribute__((ext_vector_type(8)));
typedef float  f32x4_t  __attribute__((ext_vector_type(4)));

static __device__ __forceinline__ float sspf(float x) {
    return fmaxf(x, 0.0f) + __logf(1.0f + __expf(-fabsf(x))) - LOG2F_;
}
static __device__ __forceinline__ unsigned pack2h(__bf16 a, __bf16 b) {
    union { __bf16 h[2]; unsigned u; } un; un.h[0] = a; un.h[1] = b; return un.u;
}
static __device__ __forceinline__ unsigned pack2f(float a, float b) {
    return pack2h((__bf16)a, (__bf16)b);
}

// ---------------------------------------------------------------------------
// K0 prep: weight conversion into ws (u32 = packed bf16 pairs).
//   W1B [128][32]u32: W_f1 [g][50] -> bf16, K zero-padded to 64.     @0
//   W2B [128][64]u32: W_f2 -> single bf16.                           @4096
//   L in {in2f, f2out, dense}: hi @12288+L*16384, lo = hi+8192 ([128][64]u32).
// ---------------------------------------------------------------------------
__global__ __launch_bounds__(256) void prep_kernel(
    const float* __restrict__ W1, const float* __restrict__ W2,
    const float* __restrict__ Wa, const float* __restrict__ Wb,
    const float* __restrict__ Wc, unsigned* __restrict__ prep)
{
    for (int i = blockIdx.x * 256 + threadIdx.x; i < 36864; i += gridDim.x * 256) {
        if (i < 4096) {
            int g = i >> 5, u = i & 31, k = 2 * u;
            float a = (k < 50)     ? W1[g * 50 + k]     : 0.0f;
            float b = (k + 1 < 50) ? W1[g * 50 + k + 1] : 0.0f;
            prep[i] = pack2f(a, b);
        } else if (i < 12288) {
            int j = i - 4096;
            float2 w = ((const float2*)W2)[j];
            prep[i] = pack2f(w.x, w.y);
        } else {
            int j = i - 12288;
            int L = j >> 13, r = j & 8191;
            const float* src = (L == 0) ? Wa : (L == 1) ? Wb : Wc;
            float2 w = ((const float2*)src)[r];
            __bf16 h0 = (__bf16)w.x, h1 = (__bf16)w.y;
            unsigned* H = prep + 12288 + L * 16384;
            H[r]        = pack2h(h0, h1);
            H[r + 8192] = pack2f(w.x - (float)h0, w.y - (float)h1);
        }
    }
}

// ---------------------------------------------------------------------------
// mgemm2: one or two chained dense layers on 16 atom-rows per block.
//   L1: t = ssp^n1(A @ W1^T + b1);  (two_layer) out = ssp^n2(t @ W2^T + b2)
// 256 thr = 4 waves; wave w owns f in [32w,32w+32) (ft tiles 2w,2w+1).
// W fragments read DIRECTLY from prep (per-wave disjoint f -> no LDS for W).
// LDS: Ah[16][136]bf16 @0, Al @1088dw — reused as Th/Tl for layer 2.
// Total 2176 dw = 8704 B. In-place safe (A may == C): A fully staged first.
// ---------------------------------------------------------------------------
__global__ __launch_bounds__(256, 4) void mgemm2_kernel(
    const float* A,
    const unsigned* __restrict__ W1h, const unsigned* __restrict__ W1l,
    const float* __restrict__ bias1, int nssp1,
    const unsigned* __restrict__ W2h, const unsigned* __restrict__ W2l,
    const float* __restrict__ bias2, int nssp2,
    int two_layer, float* C)
{
    extern __shared__ float smf[];
    __bf16* Ah = (__bf16*)smf;              // [16][136]
    __bf16* Al = (__bf16*)(smf + 1088);
    unsigned* AhU = (unsigned*)Ah;
    unsigned* AlU = (unsigned*)Al;

    const int t = threadIdx.x;
    const int atom0 = blockIdx.x * 16;
    const int w = t >> 6, l = t & 63, m = l & 15, q = l >> 4;

    // stage A hi/lo: 512 float4, 2 per thread
    {
        const float4* A4 = (const float4*)(A + (size_t)atom0 * 128);
        #pragma unroll
        for (int r = 0; r < 2; ++r) {
            int lin4 = r * 256 + t;
            int a = lin4 >> 5, k4 = lin4 & 31;
            float4 xv = A4[lin4];
            __bf16 h0=(__bf16)xv.x, h1=(__bf16)xv.y, h2=(__bf16)xv.z, h3=(__bf16)xv.w;
            int idx = a * 68 + 2 * k4;
            AhU[idx]     = pack2h(h0, h1);
            AhU[idx + 1] = pack2h(h2, h3);
            AlU[idx]     = pack2f(xv.x - (float)h0, xv.y - (float)h1);
            AlU[idx + 1] = pack2f(xv.z - (float)h2, xv.w - (float)h3);
        }
    }
    __syncthreads();

    // ---- layer 1 ----
    bf16x8_t ah[4], al[4];
    #pragma unroll
    for (int kk = 0; kk < 4; ++kk) {
        int off = m * 136 + 32 * kk + 8 * q;
        ah[kk] = *(const bf16x8_t*)&Ah[off];
        al[kk] = *(const bf16x8_t*)&Al[off];
    }
    f32x4_t acc[2];
    int fidx[2];
    #pragma unroll
    for (int ft = 0; ft < 2; ++ft) {
        fidx[ft] = 16 * (2 * w + ft) + m;
        float b = bias1 ? bias1[fidx[ft]] : 0.0f;
        acc[ft] = (f32x4_t){b, b, b, b};
    }
    #pragma unroll
    for (int ft = 0; ft < 2; ++ft) {
        #pragma unroll
        for (int kk = 0; kk < 4; ++kk) {
            int wo = fidx[ft] * 64 + 16 * kk + 4 * q;
            bf16x8_t wh = *(const bf16x8_t*)(W1h + wo);
            bf16x8_t wl = *(const bf16x8_t*)(W1l + wo);
            acc[ft] = __builtin_amdgcn_mfma_f32_16x16x32_bf16(ah[kk], wh, acc[ft], 0, 0, 0);
            acc[ft] = __builtin_amdgcn_mfma_f32_16x16x32_bf16(ah[kk], wl, acc[ft], 0, 0, 0);
            acc[ft] = __builtin_amdgcn_mfma_f32_16x16x32_bf16(al[kk], wh, acc[ft], 0, 0, 0);
        }
    }
    #pragma unroll
    for (int ft = 0; ft < 2; ++ft)
        #pragma unroll
        for (int r = 0; r < 4; ++r) {
            float o = acc[ft][r];
            if (nssp1 >= 1) o = sspf(o);
            if (nssp1 >= 2) o = sspf(o);
            acc[ft][r] = o;
        }

    if (!two_layer) {
        #pragma unroll
        for (int ft = 0; ft < 2; ++ft)
            #pragma unroll
            for (int r = 0; r < 4; ++r)
                C[(size_t)(atom0 + 4 * q + r) * 128 + fidx[ft]] = acc[ft][r];
        return;
    }

    // ---- t -> LDS (reuse Ah/Al), then layer 2 ----
    __syncthreads();   // everyone's A-frag reads done
    #pragma unroll
    for (int ft = 0; ft < 2; ++ft)
        #pragma unroll
        for (int r = 0; r < 4; ++r) {
            float o = acc[ft][r];
            __bf16 hh = (__bf16)o;
            Ah[(4 * q + r) * 136 + fidx[ft]] = hh;
            Al[(4 * q + r) * 136 + fidx[ft]] = (__bf16)(o - (float)hh);
        }
    __syncthreads();

    #pragma unroll
    for (int kk = 0; kk < 4; ++kk) {
        int off = m * 136 + 32 * kk + 8 * q;
        ah[kk] = *(const bf16x8_t*)&Ah[off];
        al[kk] = *(const bf16x8_t*)&Al[off];
    }
    #pragma unroll
    for (int ft = 0; ft < 2; ++ft) {
        float b = bias2 ? bias2[fidx[ft]] : 0.0f;
        acc[ft] = (f32x4_t){b, b, b, b};
    }
    #pragma unroll
    for (int ft = 0; ft < 2; ++ft) {
        #pragma unroll
        for (int kk = 0; kk < 4; ++kk) {
            int wo = fidx[ft] * 64 + 16 * kk + 4 * q;
            bf16x8_t wh = *(const bf16x8_t*)(W2h + wo);
            bf16x8_t wl = *(const bf16x8_t*)(W2l + wo);
            acc[ft] = __builtin_amdgcn_mfma_f32_16x16x32_bf16(ah[kk], wh, acc[ft], 0, 0, 0);
            acc[ft] = __builtin_amdgcn_mfma_f32_16x16x32_bf16(ah[kk], wl, acc[ft], 0, 0, 0);
            acc[ft] = __builtin_amdgcn_mfma_f32_16x16x32_bf16(al[kk], wh, acc[ft], 0, 0, 0);
        }
    }
    #pragma unroll
    for (int ft = 0; ft < 2; ++ft)
        #pragma unroll
        for (int r = 0; r < 4; ++r) {
            float o = acc[ft][r];
            if (nssp2 >= 1) o = sspf(o);
            if (nssp2 >= 2) o = sspf(o);
            C[(size_t)(atom0 + 4 * q + r) * 128 + fidx[ft]] = o;
        }
}

// ---------------------------------------------------------------------------
// Interaction: 1 atom/block (64 pairs), 256 thr = 4 waves, MFMA bf16.
// fij loaded DIRECTLY into A-fragments from global (no LDS staging);
// W2 + y-gather prefetched into registers before phase A.
// LDS (dwords, 18080 = 72320 B -> 2 blk/CU):
//   Hh[64][136]bf16 @0, Hl @4352
//   U @8704: phA W1U[128][36]u32 (4608dw) | phB W2U[128][68]u32 (8704dw)
//   cb[64] @17408, nb[64] @17472, vacc[4][136] @17536
// ---------------------------------------------------------------------------
__global__ __launch_bounds__(256, 2) void interaction_kernel(
    const float* __restrict__ rij, const int* __restrict__ nbrs,
    const float* __restrict__ mask, const float* __restrict__ fij,
    const float* __restrict__ b1, const float* __restrict__ b2,
    const unsigned* __restrict__ W1B,   // prep [128][32] u32
    const unsigned* __restrict__ W2B,   // prep [128][64] u32
    const float* __restrict__ y, float* __restrict__ v)
{
    extern __shared__ float smf[];
    __bf16*   Hh  = (__bf16*)smf;               // [64][136]
    __bf16*   Hl  = (__bf16*)(smf + 4352);
    unsigned* W1U = (unsigned*)(smf + 8704);    // [128][36]
    __bf16*   W1L = (__bf16*)W1U;               // [128][72]
    unsigned* W2U = (unsigned*)(smf + 8704);    // [128][68] (union)
    __bf16*   W2L = (__bf16*)W2U;               // [128][136]
    float*    cb  = smf + 17408;
    int*      nb  = (int*)(smf + 17472);
    float*    vacc = smf + 17536;               // [4][136]

    const int t  = threadIdx.x;
    const int a  = blockIdx.x;
    const int bi = a >> 10;
    const int p0 = a * 64;
    const int w  = t >> 6, l = t & 63, m = l & 15, q = l >> 4;

    // ---- stage cb/nb + W1 copy; prefetch W2 into regs ----
    if (t < 64) {
        float r = rij[p0 + t];
        cb[t] = (r <= RCUT) ? mask[p0 + t] : 0.0f;
        nb[t] = (bi << 10) + nbrs[p0 + t];
    }
    for (int i = t; i < 544; i += 256) vacc[i] = 0.0f;
    #pragma unroll
    for (int r = 0; r < 4; ++r) {                  // W1: 1024 uint4 copies
        int lin4 = r * 256 + t;
        int g = lin4 >> 3, u4 = lin4 & 7;
        *(uint4*)&W1U[g * 36 + 4 * u4] = *(const uint4*)(W1B + g * 32 + 4 * u4);
    }
    uint4 w2r[8];
    #pragma unroll
    for (int r = 0; r < 8; ++r) {                  // W2 -> regs (LDS after B2)
        int lin4 = r * 256 + t;
        int f = lin4 >> 4, u4 = lin4 & 15;
        w2r[r] = *(const uint4*)(W2B + f * 64 + 4 * u4);
    }
    __syncthreads();                               // B1

    // ---- fij direct to A-fragments (rows are 8B-aligned: 50*4=200B) ----
    bf16x8_t fah[2], fal[2];
    {
        const float* frow = fij + (size_t)(p0 + 16 * w + m) * 50;
        float kv[16];
        #pragma unroll
        for (int j2 = 0; j2 < 4; ++j2) {           // kq0: k = 8q..8q+7 (<50)
            float2 xv = *(const float2*)(frow + 8 * q + 2 * j2);
            kv[2 * j2] = xv.x; kv[2 * j2 + 1] = xv.y;
        }
        #pragma unroll
        for (int j2 = 0; j2 < 4; ++j2) {           // kq1: k = 32+8q+2j2
            int k = 32 + 8 * q + 2 * j2;
            float2 xv = (k < 50) ? *(const float2*)(frow + k) : float2{0.0f, 0.0f};
            kv[8 + 2 * j2] = xv.x; kv[9 + 2 * j2] = xv.y;
        }
        union { __bf16 h[16]; bf16x8_t v2[2]; } uh, ul;
        #pragma unroll
        for (int k = 0; k < 16; ++k) {
            __bf16 hi = (__bf16)kv[k];
            uh.h[k] = hi;
            ul.h[k] = (__bf16)(kv[k] - (float)hi);
        }
        fah[0] = uh.v2[0]; fah[1] = uh.v2[1];
        fal[0] = ul.v2[0]; fal[1] = ul.v2[1];
    }

    // ---- prefetch y-gather + biases (fly during phase A) ----
    float cr[4]; const float* yp[4];
    #pragma unroll
    for (int r = 0; r < 4; ++r) {
        int nn = 16 * w + 4 * q + r;
        cr[r] = cb[nn];
        yp[r] = y + (size_t)nb[nn] * 128;
    }
    float yv[8][4], bb2[8], bb1[8];
    #pragma unroll
    for (int ft = 0; ft < 8; ++ft) {
        bb2[ft] = b2[16 * ft + m];
        bb1[ft] = b1[16 * ft + m];
        #pragma unroll
        for (int r = 0; r < 4; ++r) yv[ft][r] = yp[r][16 * ft + m];
    }

    // ---- phase A: H = ssp(fij @ W1^T + b1), K=64 ----
    #pragma unroll
    for (int gt = 0; gt < 8; ++gt) {
        int g = 16 * gt + m;
        bf16x8_t wb0 = *(const bf16x8_t*)&W1L[g * 72 + 8 * q];
        bf16x8_t wb1 = *(const bf16x8_t*)&W1L[g * 72 + 32 + 8 * q];
        f32x4_t acc = {bb1[gt], bb1[gt], bb1[gt], bb1[gt]};
        acc = __builtin_amdgcn_mfma_f32_16x16x32_bf16(fah[0], wb0, acc, 0, 0, 0);
        acc = __builtin_amdgcn_mfma_f32_16x16x32_bf16(fal[0], wb0, acc, 0, 0, 0);
        acc = __builtin_amdgcn_mfma_f32_16x16x32_bf16(fah[1], wb1, acc, 0, 0, 0);
        acc = __builtin_amdgcn_mfma_f32_16x16x32_bf16(fal[1], wb1, acc, 0, 0, 0);
        #pragma unroll
        for (int r = 0; r < 4; ++r) {
            int n2 = 16 * w + 4 * q + r;
            float hv = sspf(acc[r]);
            __bf16 hhv = (__bf16)hv;
            Hh[n2 * 136 + g] = hhv;
            Hl[n2 * 136 + g] = (__bf16)(hv - (float)hhv);
        }
    }
    __syncthreads();                               // B2 (W1 reads done)

    // ---- W2 regs -> LDS ----
    #pragma unroll
    for (int r = 0; r < 8; ++r) {
        int lin4 = r * 256 + t;
        int f = lin4 >> 4, u4 = lin4 & 15;
        *(uint4*)&W2U[f * 68 + 4 * u4] = w2r[r];
    }
    __syncthreads();                               // B3

    // ---- phase B: Wm = H @ W2^T + b2, fused gather/aggregate ----
    {
        bf16x8_t hhf[4], hlf[4];
        #pragma unroll
        for (int kq = 0; kq < 4; ++kq) {
            int off = (16 * w + m) * 136 + 32 * kq + 8 * q;
            hhf[kq] = *(const bf16x8_t*)&Hh[off];
            hlf[kq] = *(const bf16x8_t*)&Hl[off];
        }
        #pragma unroll
        for (int ft = 0; ft < 8; ++ft) {
            int f = 16 * ft + m;
            f32x4_t acc = {bb2[ft], bb2[ft], bb2[ft], bb2[ft]};
            #pragma unroll
            for (int kq = 0; kq < 4; ++kq) {
                bf16x8_t wb = *(const bf16x8_t*)&W2L[f * 136 + 32 * kq + 8 * q];
                acc = __builtin_amdgcn_mfma_f32_16x16x32_bf16(hhf[kq], wb, acc, 0, 0, 0);
                acc = __builtin_amdgcn_mfma_f32_16x16x32_bf16(hlf[kq], wb, acc, 0, 0, 0);
            }
            float s = 0.0f;
            #pragma unroll
            for (int r = 0; r < 4; ++r)
                s = fmaf(cr[r] * yv[ft][r], acc[r], s);
            s += __shfl_xor(s, 16);
            s += __shfl_xor(s, 32);
            if (q == 0) vacc[w * 136 + f] += s;
        }
    }
    __syncthreads();                               // B4
    if (t < 128)
        v[(size_t)a * 128 + t] =
            vacc[t] + vacc[136 + t] + vacc[272 + t] + vacc[408 + t];
}

// ---------------------------------------------------------------------------
extern "C" void kernel_launch(void* const* d_in, const int* in_sizes, int n_in,
                              void* d_out, int out_size, void* d_ws, size_t ws_size,
                              hipStream_t stream) {
    const float* x        = (const float*)d_in[0];
    const float* rij      = (const float*)d_in[1];
    const int*   nbrs     = (const int*)  d_in[2];
    const float* mask     = (const float*)d_in[3];
    const float* fij      = (const float*)d_in[4];
    const float* W_f1     = (const float*)d_in[6];
    const float* b_f1     = (const float*)d_in[7];
    const float* W_f2     = (const float*)d_in[8];
    const float* b_f2     = (const float*)d_in[9];
    const float* W_in2f   = (const float*)d_in[5];
    const float* b_f2out  = (const float*)d_in[11];
    const float* W_f2out  = (const float*)d_in[10];
    const float* W_dense  = (const float*)d_in[12];
    const float* b_dense  = (const float*)d_in[13];
    float* out = (float*)d_out;

    // ws: y [8192][128] f32 @0 (4 MB) | prep 240 KB @4 MB.
    float*    y    = (float*)d_ws;
    unsigned* prep = (unsigned*)((char*)d_ws + (4u << 20));
    const unsigned* W1B     = prep;
    const unsigned* W2B     = prep + 4096;
    const unsigned* in2f_h  = prep + 12288, *in2f_l  = prep + 20480;
    const unsigned* f2out_h = prep + 28672, *f2out_l = prep + 36864;
    const unsigned* dense_h = prep + 45056, *dense_l = prep + 53248;

    const int MG2_LDS = 2176 * 4;    // 8704 B
    const int INT_LDS = 18080 * 4;   // 72320 B
    (void)hipFuncSetAttribute((const void*)interaction_kernel,
        hipFuncAttributeMaxDynamicSharedMemorySize, INT_LDS);

    // K0: weight prep
    prep_kernel<<<144, 256, 0, stream>>>(W_f1, W_f2, W_in2f, W_f2out, W_dense, prep);
    // K1: y = x @ W_in2f^T (single layer)
    mgemm2_kernel<<<512, 256, MG2_LDS, stream>>>(
        x, in2f_h, in2f_l, nullptr, 0, nullptr, nullptr, nullptr, 0, 0, y);
    // K2: filter net + cutoff + gather + aggregate -> d_out
    interaction_kernel<<<8192, 256, INT_LDS, stream>>>(
        rij, nbrs, mask, fij, b_f1, b_f2, W1B, W2B, y, out);
    // K3 (fused): out = (ssp(ssp(v@W_f2out^T+b)))@W_dense^T + b_dense, in-place
    mgemm2_kernel<<<512, 256, MG2_LDS, stream>>>(
        out, f2out_h, f2out_l, b_f2out, 2, dense_h, dense_l, b_dense, 0, 1, out);
}

// Round 8
// 279.158 us; speedup vs baseline: 1.3208x; 1.3208x over previous
//
#include <hip/hip_runtime.h>
#include <math.h>

// SchNet interaction, MFMA bf16-split, low-barrier/f-split design.
// Nb=8, Na=1024, Nnbh=64, A=F=128, S=50.

#define RCUT  5.0f
#define LOG2F_ 0.69314718055994530942f

typedef __bf16 bf16x8_t __attribute__((ext_vector_type(8)));
typedef float  f32x4_t  __attribute__((ext_vector_type(4)));

static __device__ __forceinline__ float sspf(float x) {
    return fmaxf(x, 0.0f) + __logf(1.0f + __expf(-fabsf(x))) - LOG2F_;
}
static __device__ __forceinline__ unsigned pack2h(__bf16 a, __bf16 b) {
    union { __bf16 h[2]; unsigned u; } un; un.h[0] = a; un.h[1] = b; return un.u;
}
static __device__ __forceinline__ unsigned pack2f(float a, float b) {
    return pack2h((__bf16)a, (__bf16)b);
}

// ---------------------------------------------------------------------------
// K1: y = x @ W_in2f^T (hi/lo split, W converted inline from fp32) + prep
// side job (bf16 weight conversion for K2/K3 into ws).
// Block = 16 atoms, 256 thr = 4 waves; wave w owns f in [32w, 32w+32).
// prep layout (u32): W1B[128][32] @0 (K-padded 64), W2B[128][64] @4096,
//   f2out hi @28672 / lo @36864, dense hi @45056 / lo @53248.
// ---------------------------------------------------------------------------
__global__ __launch_bounds__(256, 4) void k1_prep_kernel(
    const float* __restrict__ x, const float* __restrict__ Wf,  // [128][128] fp32
    float* __restrict__ yout,
    const float* __restrict__ W1, const float* __restrict__ W2,
    const float* __restrict__ Wb, const float* __restrict__ Wc,
    unsigned* __restrict__ prep)
{
    __shared__ __bf16 Ah[16 * 136];
    __shared__ __bf16 Al[16 * 136];

    const int t = threadIdx.x;
    const int atom0 = blockIdx.x * 16;
    const int l = t & 63, m = l & 15, q = l >> 4;
    const int w = t >> 6;
    const int f0 = 32 * w + m;
    const int f1 = f0 + 16;

    // ---- prep side job: one item per thread (28672 items < 131072 threads)
    {
        int i = blockIdx.x * 256 + t;
        if (i < 4096) {                       // W1B: [g][32]u32, K-pad to 64
            int g = i >> 5, u = i & 31, k = 2 * u;
            float a = (k < 50)     ? W1[g * 50 + k]     : 0.0f;
            float b = (k + 1 < 50) ? W1[g * 50 + k + 1] : 0.0f;
            prep[i] = pack2f(a, b);
        } else if (i < 12288) {               // W2B single bf16
            int j = i - 4096;
            float2 wv = ((const float2*)W2)[j];
            prep[i] = pack2f(wv.x, wv.y);
        } else if (i < 28672) {               // f2out / dense hi+lo
            int j = i - 12288;
            int L = j >> 13, r = j & 8191;
            const float* src = (L == 0) ? Wb : Wc;
            float2 wv = ((const float2*)src)[r];
            __bf16 h0 = (__bf16)wv.x, h1 = (__bf16)wv.y;
            unsigned* H = prep + 28672 + L * 16384;
            H[r]        = pack2h(h0, h1);
            H[r + 8192] = pack2f(wv.x - (float)h0, wv.y - (float)h1);
        }
    }

    // ---- stage x hi/lo into LDS ----
    {
        const float4* A4 = (const float4*)(x + (size_t)atom0 * 128);
        unsigned* AhU = (unsigned*)Ah;
        unsigned* AlU = (unsigned*)Al;
        #pragma unroll
        for (int r = 0; r < 2; ++r) {
            int lin4 = r * 256 + t;
            int a = lin4 >> 5, k4 = lin4 & 31;
            float4 xv = A4[lin4];
            __bf16 h0=(__bf16)xv.x, h1=(__bf16)xv.y, h2=(__bf16)xv.z, h3=(__bf16)xv.w;
            int idx = a * 68 + 2 * k4;
            AhU[idx]     = pack2h(h0, h1);
            AhU[idx + 1] = pack2h(h2, h3);
            AlU[idx]     = pack2f(xv.x - (float)h0, xv.y - (float)h1);
            AlU[idx + 1] = pack2f(xv.z - (float)h2, xv.w - (float)h3);
        }
    }
    __syncthreads();

    f32x4_t acc0 = {0.f, 0.f, 0.f, 0.f};
    f32x4_t acc1 = {0.f, 0.f, 0.f, 0.f};
    #pragma unroll
    for (int kk = 0; kk < 4; ++kk) {
        bf16x8_t ah = *(const bf16x8_t*)&Ah[m * 136 + 32 * kk + 8 * q];
        bf16x8_t al = *(const bf16x8_t*)&Al[m * 136 + 32 * kk + 8 * q];
        #pragma unroll
        for (int ftl = 0; ftl < 2; ++ftl) {
            const float* wr = Wf + (size_t)(ftl ? f1 : f0) * 128 + 32 * kk + 8 * q;
            float4 wa = *(const float4*)wr;
            float4 wb4 = *(const float4*)(wr + 4);
            float wv[8] = {wa.x, wa.y, wa.z, wa.w, wb4.x, wb4.y, wb4.z, wb4.w};
            union { __bf16 h[8]; bf16x8_t v8; } wh, wl;
            #pragma unroll
            for (int k = 0; k < 8; ++k) {
                __bf16 hi = (__bf16)wv[k];
                wh.h[k] = hi;
                wl.h[k] = (__bf16)(wv[k] - (float)hi);
            }
            f32x4_t& acc = ftl ? acc1 : acc0;
            acc = __builtin_amdgcn_mfma_f32_16x16x32_bf16(ah, wh.v8, acc, 0, 0, 0);
            acc = __builtin_amdgcn_mfma_f32_16x16x32_bf16(ah, wl.v8, acc, 0, 0, 0);
            acc = __builtin_amdgcn_mfma_f32_16x16x32_bf16(al, wh.v8, acc, 0, 0, 0);
        }
    }
    #pragma unroll
    for (int r = 0; r < 4; ++r) {
        size_t row = (size_t)(atom0 + 4 * q + r) * 128;
        yout[row + f0] = acc0[r];
        yout[row + f1] = acc1[r];
    }
}

// ---------------------------------------------------------------------------
// K2 interaction: 1 atom/block (64 pairs), 256 thr = 4 waves.
// Wave w owns f/g range [32w, 32w+32) in BOTH phases; weights read directly
// from prep (global, L2-hot) into B-frags; fij read directly into A-frags.
// ONE __syncthreads (H handoff). Epilogue: per-wave complete n-sum -> direct
// v write (shfl over q). LDS 35328 B static -> 4 blocks/CU.
// Frag maps (m89-verified): A[m=lane&15][k=q*8+j], B[k=q*8+j][n=lane&15],
// D col=lane&15, row=q*4+reg.
// ---------------------------------------------------------------------------
__global__ __launch_bounds__(256, 4) void interaction_kernel(
    const float* __restrict__ rij, const int* __restrict__ nbrs,
    const float* __restrict__ mask, const float* __restrict__ fij,
    const float* __restrict__ b1, const float* __restrict__ b2,
    const unsigned* __restrict__ W1B,   // [128][32] u32 (bf16 pairs, K=64 pad)
    const unsigned* __restrict__ W2B,   // [128][64] u32 (bf16 pairs)
    const float* __restrict__ y, float* __restrict__ v)
{
    __shared__ __bf16 Hh[64 * 136];
    __shared__ __bf16 Hl[64 * 136];
    __shared__ float  cb[64];
    __shared__ int    nb[64];

    const int t  = threadIdx.x;
    const int a  = blockIdx.x;
    const int bi = a >> 10;
    const int p0 = a * 64;
    const int w = t >> 6, l = t & 63, m = l & 15, q = l >> 4;
    const int f0 = 32 * w + m;
    const int f1 = f0 + 16;

    if (t < 64) {
        float r = rij[p0 + t];
        cb[t] = (r <= RCUT) ? mask[p0 + t] : 0.0f;
        nb[t] = (bi << 10) + nbrs[p0 + t];
    }

    const float bb1_0 = b1[f0], bb1_1 = b1[f1];
    const float bb2_0 = b2[f0], bb2_1 = b2[f1];

    // W1 B-frags for this wave's g columns (live across mt: 4 frags)
    bf16x8_t w1f00 = *(const bf16x8_t*)(W1B + f0 * 32 + 4 * q);
    bf16x8_t w1f01 = *(const bf16x8_t*)(W1B + f0 * 32 + 16 + 4 * q);
    bf16x8_t w1f10 = *(const bf16x8_t*)(W1B + f1 * 32 + 4 * q);
    bf16x8_t w1f11 = *(const bf16x8_t*)(W1B + f1 * 32 + 16 + 4 * q);

    // ---- phase A: H[n][g] = ssp(fij @ W1^T + b1), per 16-row mt tile ----
    #pragma unroll 1
    for (int mt = 0; mt < 4; ++mt) {
        const float* frow = fij + (size_t)(p0 + 16 * mt + m) * 50;
        float kv[16];
        #pragma unroll
        for (int j2 = 0; j2 < 4; ++j2) {           // k = 8q+2j2 (+1), all < 32
            float2 xv = *(const float2*)(frow + 8 * q + 2 * j2);
            kv[2 * j2] = xv.x; kv[2 * j2 + 1] = xv.y;
        }
        #pragma unroll
        for (int j2 = 0; j2 < 4; ++j2) {           // k = 32+8q+2j2, pad >= 50
            int k = 32 + 8 * q + 2 * j2;
            float2 xv = make_float2(0.f, 0.f);
            if (k < 50) xv = *(const float2*)(frow + k);
            kv[8 + 2 * j2] = xv.x; kv[9 + 2 * j2] = xv.y;
        }
        union { __bf16 h[16]; bf16x8_t v8[2]; } uh, ul;
        #pragma unroll
        for (int k = 0; k < 16; ++k) {
            __bf16 hi = (__bf16)kv[k];
            uh.h[k] = hi;
            ul.h[k] = (__bf16)(kv[k] - (float)hi);
        }
        f32x4_t acc0 = {bb1_0, bb1_0, bb1_0, bb1_0};
        f32x4_t acc1 = {bb1_1, bb1_1, bb1_1, bb1_1};
        acc0 = __builtin_amdgcn_mfma_f32_16x16x32_bf16(uh.v8[0], w1f00, acc0, 0, 0, 0);
        acc0 = __builtin_amdgcn_mfma_f32_16x16x32_bf16(ul.v8[0], w1f00, acc0, 0, 0, 0);
        acc0 = __builtin_amdgcn_mfma_f32_16x16x32_bf16(uh.v8[1], w1f01, acc0, 0, 0, 0);
        acc0 = __builtin_amdgcn_mfma_f32_16x16x32_bf16(ul.v8[1], w1f01, acc0, 0, 0, 0);
        acc1 = __builtin_amdgcn_mfma_f32_16x16x32_bf16(uh.v8[0], w1f10, acc1, 0, 0, 0);
        acc1 = __builtin_amdgcn_mfma_f32_16x16x32_bf16(ul.v8[0], w1f10, acc1, 0, 0, 0);
        acc1 = __builtin_amdgcn_mfma_f32_16x16x32_bf16(uh.v8[1], w1f11, acc1, 0, 0, 0);
        acc1 = __builtin_amdgcn_mfma_f32_16x16x32_bf16(ul.v8[1], w1f11, acc1, 0, 0, 0);
        #pragma unroll
        for (int r = 0; r < 4; ++r) {
            int n = 16 * mt + 4 * q + r;
            float h0v = sspf(acc0[r]);
            float h1v = sspf(acc1[r]);
            __bf16 hh0 = (__bf16)h0v, hh1 = (__bf16)h1v;
            Hh[n * 136 + f0] = hh0;
            Hl[n * 136 + f0] = (__bf16)(h0v - (float)hh0);
            Hh[n * 136 + f1] = hh1;
            Hl[n * 136 + f1] = (__bf16)(h1v - (float)hh1);
        }
    }
    __syncthreads();   // the ONLY barrier: H (and cb/nb) handoff

    // ---- phase B: Wm = H @ W2^T + b2, fused gather/aggregate ----
    float pv0 = 0.0f, pv1 = 0.0f;
    #pragma unroll 1
    for (int mt = 0; mt < 4; ++mt) {
        f32x4_t acc0 = {bb2_0, bb2_0, bb2_0, bb2_0};
        f32x4_t acc1 = {bb2_1, bb2_1, bb2_1, bb2_1};
        #pragma unroll
        for (int kq = 0; kq < 4; ++kq) {
            int hoff = (16 * mt + m) * 136 + 32 * kq + 8 * q;
            bf16x8_t hh = *(const bf16x8_t*)&Hh[hoff];
            bf16x8_t hl = *(const bf16x8_t*)&Hl[hoff];
            bf16x8_t w20 = *(const bf16x8_t*)(W2B + f0 * 64 + 16 * kq + 4 * q);
            bf16x8_t w21 = *(const bf16x8_t*)(W2B + f1 * 64 + 16 * kq + 4 * q);
            acc0 = __builtin_amdgcn_mfma_f32_16x16x32_bf16(hh, w20, acc0, 0, 0, 0);
            acc0 = __builtin_amdgcn_mfma_f32_16x16x32_bf16(hl, w20, acc0, 0, 0, 0);
            acc1 = __builtin_amdgcn_mfma_f32_16x16x32_bf16(hh, w21, acc1, 0, 0, 0);
            acc1 = __builtin_amdgcn_mfma_f32_16x16x32_bf16(hl, w21, acc1, 0, 0, 0);
        }
        #pragma unroll
        for (int r = 0; r < 4; ++r) {
            int n = 16 * mt + 4 * q + r;
            float cn = cb[n];
            const float* yrow = y + (size_t)nb[n] * 128;
            pv0 = fmaf(cn * yrow[f0], acc0[r], pv0);
            pv1 = fmaf(cn * yrow[f1], acc1[r], pv1);
        }
    }
    pv0 += __shfl_xor(pv0, 16);
    pv0 += __shfl_xor(pv0, 32);
    pv1 += __shfl_xor(pv1, 16);
    pv1 += __shfl_xor(pv1, 32);
    if (l < 16) {
        v[(size_t)a * 128 + f0] = pv0;
        v[(size_t)a * 128 + f1] = pv1;
    }
}

// ---------------------------------------------------------------------------
// K3: two chained dense layers (mgemm2, unchanged from R7 — verified).
// ---------------------------------------------------------------------------
__global__ __launch_bounds__(256, 4) void mgemm2_kernel(
    const float* A,
    const unsigned* __restrict__ W1h, const unsigned* __restrict__ W1l,
    const float* __restrict__ bias1, int nssp1,
    const unsigned* __restrict__ W2h, const unsigned* __restrict__ W2l,
    const float* __restrict__ bias2, int nssp2,
    int two_layer, float* C)
{
    extern __shared__ float smf[];
    __bf16* Ah = (__bf16*)smf;              // [16][136]
    __bf16* Al = (__bf16*)(smf + 1088);
    unsigned* AhU = (unsigned*)Ah;
    unsigned* AlU = (unsigned*)Al;

    const int t = threadIdx.x;
    const int atom0 = blockIdx.x * 16;
    const int w = t >> 6, l = t & 63, m = l & 15, q = l >> 4;

    {
        const float4* A4 = (const float4*)(A + (size_t)atom0 * 128);
        #pragma unroll
        for (int r = 0; r < 2; ++r) {
            int lin4 = r * 256 + t;
            int a = lin4 >> 5, k4 = lin4 & 31;
            float4 xv = A4[lin4];
            __bf16 h0=(__bf16)xv.x, h1=(__bf16)xv.y, h2=(__bf16)xv.z, h3=(__bf16)xv.w;
            int idx = a * 68 + 2 * k4;
            AhU[idx]     = pack2h(h0, h1);
            AhU[idx + 1] = pack2h(h2, h3);
            AlU[idx]     = pack2f(xv.x - (float)h0, xv.y - (float)h1);
            AlU[idx + 1] = pack2f(xv.z - (float)h2, xv.w - (float)h3);
        }
    }
    __syncthreads();

    bf16x8_t ah[4], al[4];
    #pragma unroll
    for (int kk = 0; kk < 4; ++kk) {
        int off = m * 136 + 32 * kk + 8 * q;
        ah[kk] = *(const bf16x8_t*)&Ah[off];
        al[kk] = *(const bf16x8_t*)&Al[off];
    }
    f32x4_t acc[2];
    int fidx[2];
    #pragma unroll
    for (int ft = 0; ft < 2; ++ft) {
        fidx[ft] = 16 * (2 * w + ft) + m;
        float b = bias1 ? bias1[fidx[ft]] : 0.0f;
        acc[ft] = (f32x4_t){b, b, b, b};
    }
    #pragma unroll
    for (int ft = 0; ft < 2; ++ft) {
        #pragma unroll
        for (int kk = 0; kk < 4; ++kk) {
            int wo = fidx[ft] * 64 + 16 * kk + 4 * q;
            bf16x8_t wh = *(const bf16x8_t*)(W1h + wo);
            bf16x8_t wl = *(const bf16x8_t*)(W1l + wo);
            acc[ft] = __builtin_amdgcn_mfma_f32_16x16x32_bf16(ah[kk], wh, acc[ft], 0, 0, 0);
            acc[ft] = __builtin_amdgcn_mfma_f32_16x16x32_bf16(ah[kk], wl, acc[ft], 0, 0, 0);
            acc[ft] = __builtin_amdgcn_mfma_f32_16x16x32_bf16(al[kk], wh, acc[ft], 0, 0, 0);
        }
    }
    #pragma unroll
    for (int ft = 0; ft < 2; ++ft)
        #pragma unroll
        for (int r = 0; r < 4; ++r) {
            float o = acc[ft][r];
            if (nssp1 >= 1) o = sspf(o);
            if (nssp1 >= 2) o = sspf(o);
            acc[ft][r] = o;
        }

    if (!two_layer) {
        #pragma unroll
        for (int ft = 0; ft < 2; ++ft)
            #pragma unroll
            for (int r = 0; r < 4; ++r)
                C[(size_t)(atom0 + 4 * q + r) * 128 + fidx[ft]] = acc[ft][r];
        return;
    }

    __syncthreads();
    #pragma unroll
    for (int ft = 0; ft < 2; ++ft)
        #pragma unroll
        for (int r = 0; r < 4; ++r) {
            float o = acc[ft][r];
            __bf16 hh = (__bf16)o;
            Ah[(4 * q + r) * 136 + fidx[ft]] = hh;
            Al[(4 * q + r) * 136 + fidx[ft]] = (__bf16)(o - (float)hh);
        }
    __syncthreads();

    #pragma unroll
    for (int kk = 0; kk < 4; ++kk) {
        int off = m * 136 + 32 * kk + 8 * q;
        ah[kk] = *(const bf16x8_t*)&Ah[off];
        al[kk] = *(const bf16x8_t*)&Al[off];
    }
    #pragma unroll
    for (int ft = 0; ft < 2; ++ft) {
        float b = bias2 ? bias2[fidx[ft]] : 0.0f;
        acc[ft] = (f32x4_t){b, b, b, b};
    }
    #pragma unroll
    for (int ft = 0; ft < 2; ++ft) {
        #pragma unroll
        for (int kk = 0; kk < 4; ++kk) {
            int wo = fidx[ft] * 64 + 16 * kk + 4 * q;
            bf16x8_t wh = *(const bf16x8_t*)(W2h + wo);
            bf16x8_t wl = *(const bf16x8_t*)(W2l + wo);
            acc[ft] = __builtin_amdgcn_mfma_f32_16x16x32_bf16(ah[kk], wh, acc[ft], 0, 0, 0);
            acc[ft] = __builtin_amdgcn_mfma_f32_16x16x32_bf16(ah[kk], wl, acc[ft], 0, 0, 0);
            acc[ft] = __builtin_amdgcn_mfma_f32_16x16x32_bf16(al[kk], wh, acc[ft], 0, 0, 0);
        }
    }
    #pragma unroll
    for (int ft = 0; ft < 2; ++ft)
        #pragma unroll
        for (int r = 0; r < 4; ++r) {
            float o = acc[ft][r];
            if (nssp2 >= 1) o = sspf(o);
            if (nssp2 >= 2) o = sspf(o);
            C[(size_t)(atom0 + 4 * q + r) * 128 + fidx[ft]] = o;
        }
}

// ---------------------------------------------------------------------------
extern "C" void kernel_launch(void* const* d_in, const int* in_sizes, int n_in,
                              void* d_out, int out_size, void* d_ws, size_t ws_size,
                              hipStream_t stream) {
    const float* x        = (const float*)d_in[0];
    const float* rij      = (const float*)d_in[1];
    const int*   nbrs     = (const int*)  d_in[2];
    const float* mask     = (const float*)d_in[3];
    const float* fij      = (const float*)d_in[4];
    const float* W_in2f   = (const float*)d_in[5];
    const float* W_f1     = (const float*)d_in[6];
    const float* b_f1     = (const float*)d_in[7];
    const float* W_f2     = (const float*)d_in[8];
    const float* b_f2     = (const float*)d_in[9];
    const float* W_f2out  = (const float*)d_in[10];
    const float* b_f2out  = (const float*)d_in[11];
    const float* W_dense  = (const float*)d_in[12];
    const float* b_dense  = (const float*)d_in[13];
    float* out = (float*)d_out;

    // ws: y [8192][128] f32 @0 (4 MB) | prep 240 KB @4 MB.
    float*    y    = (float*)d_ws;
    unsigned* prep = (unsigned*)((char*)d_ws + (4u << 20));
    const unsigned* W1B     = prep;
    const unsigned* W2B     = prep + 4096;
    const unsigned* f2out_h = prep + 28672, *f2out_l = prep + 36864;
    const unsigned* dense_h = prep + 45056, *dense_l = prep + 53248;

    const int MG2_LDS = 2176 * 4;    // 8704 B

    // K1: y = x @ W_in2f^T  (+ prep side job for K2/K3 weights)
    k1_prep_kernel<<<512, 256, 0, stream>>>(
        x, W_in2f, y, W_f1, W_f2, W_f2out, W_dense, prep);
    // K2: filter net + cutoff + gather + aggregate -> d_out
    interaction_kernel<<<8192, 256, 0, stream>>>(
        rij, nbrs, mask, fij, b_f1, b_f2, W1B, W2B, y, out);
    // K3 (fused): out = ssp(ssp(v@W_f2out^T+b)) @ W_dense^T + b_dense, in-place
    mgemm2_kernel<<<512, 256, MG2_LDS, stream>>>(
        out, f2out_h, f2out_l, b_f2out, 2, dense_h, dense_l, b_dense, 0, 1, out);
}